// Round 25
// baseline (225.017 us; speedup 1.0000x reference)
//
#include <hip/hip_runtime.h>

// MPM P2G, quadratic B-spline, 3x3x3 stencil.
// Bucket-4 sort + cooperative gather (v10 = v9 with accumulate unroll x4):
//   pre-pass: counting-sort by 4-z-cell BUCKET; hist's atomicAdd RETURNS the
//             particle's rank -> scatter uses start[bucket]+rank (NO atomic).
//   gather:   v6-exact trip body (b32 dependent ws read), unrolled x4
//             (x2 won +11us in r24; deeper window for DS-latency overlap).
// No atomics in gather, write-once coalesced stores.
//
// Outputs (concatenated in d_out, fp32):
//   grids [T,G,G,G]   -> d_out[0 .. T*G^3)
//   gdef  [T,G,G,G,3] -> d_out[T*G^3 .. 4*T*G^3)

constexpr int   G       = 128;
constexpr int   CELLS   = G * G * G;      // 2,097,152
constexpr int   BUCKETS = CELLS / 4;      // 524,288 per timestep
constexpr float MINN    = -15.0f;
constexpr float EXTENT  = 40.0f;

__device__ __forceinline__ int3 base_cell(float x, float y, float z,
                                          float& fx, float& fy, float& fz)
{
    const float scale = (float)G / EXTENT;
    const float Xp = (x - MINN) * scale;
    const float Yp = (y - MINN) * scale;
    const float Zp = (z - MINN) * scale;
    int bx = (int)floorf(Xp - 0.5f);
    int by = (int)floorf(Yp - 0.5f);
    int bz = (int)floorf(Zp - 0.5f);
    // f from the UNclamped base (matches reference); clamp affects indices only
    fx = Xp - (float)bx; fy = Yp - (float)by; fz = Zp - (float)bz;
    bx = min(max(bx, 0), G - 3);
    by = min(max(by, 0), G - 3);
    bz = min(max(bz, 0), G - 3);
    return make_int3(bx, by, bz);
}

__device__ __forceinline__ float wsel(float f, int d)
{
    const float r0 = 1.5f - f, r1 = f - 1.0f, r2 = f - 0.5f;
    const float w0 = 0.5f * r0 * r0;
    const float w1 = 0.75f - r1 * r1;
    const float w2 = 0.5f * r2 * r2;
    return d == 0 ? w0 : (d == 1 ? w1 : w2);
}

// ---- K1: per-bucket histogram; atomic return value = in-bucket rank ---------
__global__ void __launch_bounds__(256)
hist_rank(const float* __restrict__ xs, int* __restrict__ arr,
          int* __restrict__ rank, int N)
{
    const int p = blockIdx.x * blockDim.x + threadIdx.x;
    const int t = blockIdx.y;
    if (p >= N) return;
    const long i = (long)t * N + p;
    float fx, fy, fz;
    int3 b = base_cell(xs[i*3], xs[i*3+1], xs[i*3+2], fx, fy, fz);
    const int bucket = (b.x << 12) + (b.y << 5) + (b.z >> 2);
    rank[i] = atomicAdd(&arr[(long)t * BUCKETS + bucket], 1);
}

// ---- K2a: per-4096-chunk exclusive scan (in place) + chunk totals -----------
__global__ void __launch_bounds__(256)
scan1(int* __restrict__ arr, int* __restrict__ sums)
{
    const int t = blockIdx.y, tid = threadIdx.x;
    int* a = arr + (long)t * BUCKETS + (long)blockIdx.x * 4096 + tid * 16;
    int local[16], s = 0;
    #pragma unroll
    for (int i = 0; i < 16; ++i) { const int v = a[i]; local[i] = s; s += v; }
    __shared__ int part[256];
    part[tid] = s;
    __syncthreads();
    const int own = s;
    for (int d = 1; d < 256; d <<= 1) {
        int v = (tid >= d) ? part[tid - d] : 0;
        __syncthreads();
        part[tid] += v;
        __syncthreads();
    }
    const int excl = part[tid] - own;
    #pragma unroll
    for (int i = 0; i < 16; ++i) a[i] = excl + local[i];
    if (tid == 255) sums[t * 128 + blockIdx.x] = part[255];
}

// ---- K2b: exclusive scan of the 128 chunk totals per timestep ---------------
__global__ void __launch_bounds__(128)
scan2(int* __restrict__ sums)
{
    const int t = blockIdx.x, tid = threadIdx.x;   // 128 threads, 1 each
    const int v = sums[t * 128 + tid];
    __shared__ int part[128];
    part[tid] = v;
    __syncthreads();
    for (int d = 1; d < 128; d <<= 1) {
        int u = (tid >= d) ? part[tid - d] : 0;
        __syncthreads();
        part[tid] += u;
        __syncthreads();
    }
    sums[t * 128 + tid] = part[tid] - v;           // exclusive
}

// ---- K3: scatter via start[bucket]+rank (no atomics) ------------------------
__global__ void __launch_bounds__(256)
scatter_cells(const float* __restrict__ xs, const float* __restrict__ def,
              const int* __restrict__ arr, const int* __restrict__ sums,
              const int* __restrict__ rank,
              float4* __restrict__ sA, float2* __restrict__ sB, int N)
{
    const int p = blockIdx.x * blockDim.x + threadIdx.x;
    const int t = blockIdx.y;
    if (p >= N) return;
    const long i = (long)t * N + p;
    const float x = xs[i*3], y = xs[i*3+1], z = xs[i*3+2];
    float fx, fy, fz;
    int3 b = base_cell(x, y, z, fx, fy, fz);
    const float Zp = (z - MINN) * ((float)G / EXTENT);
    const int bucket = (b.x << 12) + (b.y << 5) + (b.z >> 2);
    const int slot = arr[(long)t * BUCKETS + bucket]
                   + sums[t * 128 + (bucket >> 12)] + rank[i];
    const long o = (long)t * N + slot;
    sA[o] = make_float4(fx, fy, Zp, def[i*3]);
    sB[o] = make_float2(def[i*3+1], def[i*3+2]);
}

// ---- K4: v6-exact gather, accumulate unrolled x4; arr = START offsets -------
__global__ void __launch_bounds__(256)
gather_cells6(const float4* __restrict__ sA, const float2* __restrict__ sB,
              const int* __restrict__ arr, const int* __restrict__ sums,
              float* __restrict__ grids, float* __restrict__ gdef, int N)
{
    const int wid  = threadIdx.x >> 6;
    const int lane = threadIdx.x & 63;
    const int g    = lane >> 4;                  // group 0..3
    const int zl   = lane & 15;                  // z within group
    const int t = blockIdx.y;
    const int W = blockIdx.x * 4 + wid;
    const int col = W >> 1;                      // (cx,cy) column
    const int zbase = (W & 1) << 6;              // 0 or 64
    const int cy = col & (G - 1);
    const int cx = col >> 7;
    const int cz = zbase + lane;                 // lane's output z (g*16+zl)

    __shared__ int2   descBC[4][4][9];           // [wid][g][r] {begin, count}
    __shared__ float4 rec[4][4][17];             // [wid][g][slot] {bz,d0,d1,d2}
    __shared__ float  ws[4][3][4][17];           // [wid][k][g][slot]

    const int* a  = arr + (long)t * BUCKETS;
    const int* sm = sums + t * 128;
    const long pbase = (long)t * N;

    // --- 36 segment descriptors (4 groups x 9 rows), lanes 0..35 -------------
    // group window z [Z0, Z0+15] -> buckets [bb-1, bb+3]; with START offsets:
    // range = [start(bb-1), start(bb+4)) -> c0 = rb+bb-1, c1 = rb+bb+4.
    // Over-coverage is k-filtered in accumulate.
    if (lane < 36) {
        const int g2 = lane / 9;                 // magic-mul
        const int r2 = lane - 9 * g2;
        const int rx = cx - 2 + r2 / 3;
        const int ry = cy - 2 + r2 % 3;
        int beg = 0, cnt = 0;
        if (rx >= 0 && ry >= 0) {
            const int rb = (rx << 12) + (ry << 5);
            const int bb = (zbase >> 2) + (g2 << 2);
            const int c1 = rb + bb + 4;          // start of bucket past window
            const int e  = a[c1] + sm[c1 >> 12];
            const int c0 = rb + bb - 1;          // start of first window bucket
            beg = (c0 >= 0) ? (a[c0] + sm[c0 >> 12]) : 0;
            cnt = max(e - beg, 0);
        }
        descBC[wid][g2][r2] = make_int2(beg, cnt);
    }
    // same-wave DS program order: reads below see the writes above.

    // --- per-lane prefix from LDS broadcast reads ----------------------------
    const int2 d0_ = descBC[wid][g][0], d1_ = descBC[wid][g][1],
               d2_ = descBC[wid][g][2], d3_ = descBC[wid][g][3],
               d4_ = descBC[wid][g][4], d5_ = descBC[wid][g][5],
               d6_ = descBC[wid][g][6], d7_ = descBC[wid][g][7],
               d8_ = descBC[wid][g][8];
    const int p1 = d0_.y;
    const int p2 = p1 + d1_.y;
    const int p3 = p2 + d2_.y;
    const int p4 = p3 + d3_.y;
    const int p5 = p4 + d4_.y;
    const int p6 = p5 + d5_.y;
    const int p7 = p6 + d6_.y;
    const int p8 = p7 + d7_.y;
    const int tot = p8 + d8_.y;                  // group total (uniform in group)
    const int adj0 = d0_.x;
    const int adj1 = d1_.x - p1;
    const int adj2 = d2_.x - p2;
    const int adj3 = d3_.x - p3;
    const int adj4 = d4_.x - p4;
    const int adj5 = d5_.x - p5;
    const int adj6 = d6_.x - p6;
    const int adj7 = d7_.x - p7;
    const int adj8 = d8_.x - p8;

    // wave-max of the 4 group totals
    int mt = max(tot, __shfl_xor(tot, 16));
    mt = max(mt, __shfl_xor(mt, 32));

    float m = 0.f, v0 = 0.f, v1 = 0.f, v2 = 0.f;

    for (int p0 = 0; p0 < mt; p0 += 16) {
        // ---- stage: each group fills up to 16 slots, weights computed once --
        const int j = p0 + zl;
        if (j < tot) {
            const int g1_ = (j >= p1), g2_ = (j >= p2), g3_ = (j >= p3),
                      g4_ = (j >= p4), g5_ = (j >= p5), g6_ = (j >= p6),
                      g7_ = (j >= p7), g8_ = (j >= p8);
            int ad = adj0;
            ad = g1_ ? adj1 : ad;  ad = g2_ ? adj2 : ad;  ad = g3_ ? adj3 : ad;
            ad = g4_ ? adj4 : ad;  ad = g5_ ? adj5 : ad;  ad = g6_ ? adj6 : ad;
            ad = g7_ ? adj7 : ad;  ad = g8_ ? adj8 : ad;
            const int dp = 10 - g1_ - g2_ - 2*g3_ - g4_ - g5_ - 2*g6_ - g7_ - g8_;
            const int idx = j + ad;

            const float4 A = sA[pbase + idx];    // {fx, fy, Zp, d0}
            const float2 B = sB[pbase + idx];    // {d1, d2}
            const float bzf = floorf(A.z - 0.5f);
            const float fz  = A.z - bzf;
            const float wxy = wsel(A.x, dp >> 2) * wsel(A.y, dp & 3);
            const float q0 = 1.5f - fz, q1 = fz - 1.0f, q2 = fz - 0.5f;
            rec[wid][g][zl] =
                make_float4(__int_as_float((int)bzf), A.w, B.x, B.y);
            ws[wid][0][g][zl] = wxy * (0.5f * q0 * q0);
            ws[wid][1][g][zl] = wxy * (0.75f - q1 * q1);
            ws[wid][2][g][zl] = wxy * (0.5f * q2 * q2);
        }
        // ---- accumulate this batch, v6 trip body, unrolled x4 ---------------
        const int cc = min(tot - p0, 16);
        int p = 0;
        for (; p + 3 < cc; p += 4) {
            const float4 Ra = rec[wid][g][p];
            const float4 Rb = rec[wid][g][p + 1];
            const float4 Rc = rec[wid][g][p + 2];
            const float4 Rd = rec[wid][g][p + 3];
            const int ka_ = cz - __float_as_int(Ra.x);
            const int kb_ = cz - __float_as_int(Rb.x);
            const int kc_ = cz - __float_as_int(Rc.x);
            const int kd_ = cz - __float_as_int(Rd.x);
            const float wsa = ws[wid][min(max(ka_, 0), 2)][g][p];
            const float wsb = ws[wid][min(max(kb_, 0), 2)][g][p + 1];
            const float wsc = ws[wid][min(max(kc_, 0), 2)][g][p + 2];
            const float wsd = ws[wid][min(max(kd_, 0), 2)][g][p + 3];
            const float wa = ((unsigned)ka_ <= 2u) ? wsa : 0.0f;
            const float wb = ((unsigned)kb_ <= 2u) ? wsb : 0.0f;
            const float wc = ((unsigned)kc_ <= 2u) ? wsc : 0.0f;
            const float wd = ((unsigned)kd_ <= 2u) ? wsd : 0.0f;
            m  += wa;            v0 += wa * Ra.y;
            v1 += wa * Ra.z;     v2 += wa * Ra.w;
            m  += wb;            v0 += wb * Rb.y;
            v1 += wb * Rb.z;     v2 += wb * Rb.w;
            m  += wc;            v0 += wc * Rc.y;
            v1 += wc * Rc.z;     v2 += wc * Rc.w;
            m  += wd;            v0 += wd * Rd.y;
            v1 += wd * Rd.z;     v2 += wd * Rd.w;
        }
        for (; p + 1 < cc; p += 2) {
            const float4 Ra = rec[wid][g][p];
            const float4 Rb = rec[wid][g][p + 1];
            const int ka_ = cz - __float_as_int(Ra.x);
            const int kb_ = cz - __float_as_int(Rb.x);
            const float wsa = ws[wid][min(max(ka_, 0), 2)][g][p];
            const float wsb = ws[wid][min(max(kb_, 0), 2)][g][p + 1];
            const float wa = ((unsigned)ka_ <= 2u) ? wsa : 0.0f;
            const float wb = ((unsigned)kb_ <= 2u) ? wsb : 0.0f;
            m  += wa;            v0 += wa * Ra.y;
            v1 += wa * Ra.z;     v2 += wa * Ra.w;
            m  += wb;            v0 += wb * Rb.y;
            v1 += wb * Rb.z;     v2 += wb * Rb.w;
        }
        if (p < cc) {
            const float4 R = rec[wid][g][p];
            const int k  = cz - __float_as_int(R.x);
            const float wsv = ws[wid][min(max(k, 0), 2)][g][p];
            const float w = ((unsigned)k <= 2u) ? wsv : 0.0f;
            m  += w;             v0 += w * R.y;
            v1 += w * R.z;       v2 += w * R.w;
        }
    }

    // flush: lane owns cell (t, cx, cy, cz) -> write-once coalesced stores
    const long gidx = (long)t * CELLS + ((long)col << 7) + cz;
    grids[gidx]      = m;
    gdef[gidx*3 + 0] = v0;
    gdef[gidx*3 + 1] = v1;
    gdef[gidx*3 + 2] = v2;
}

// ---- last-resort fallback: direct global atomics ----------------------------
__global__ void __launch_bounds__(256)
p2g_direct(const float* __restrict__ xs, const float* __restrict__ def,
           float* __restrict__ grids, float* __restrict__ gdef, int N)
{
    const int p = blockIdx.x * blockDim.x + threadIdx.x;
    const int t = blockIdx.y;
    if (p >= N) return;
    const long i = (long)t * N + p;
    const float dx = def[i*3], dy = def[i*3+1], dz = def[i*3+2];
    float fx, fy, fz;
    int3 b = base_cell(xs[i*3], xs[i*3+1], xs[i*3+2], fx, fy, fz);
    float wx[3], wy[3], wz[3];
    wx[0] = 0.5f*(1.5f-fx)*(1.5f-fx); wx[1] = 0.75f-(fx-1.f)*(fx-1.f); wx[2] = 0.5f*(fx-0.5f)*(fx-0.5f);
    wy[0] = 0.5f*(1.5f-fy)*(1.5f-fy); wy[1] = 0.75f-(fy-1.f)*(fy-1.f); wy[2] = 0.5f*(fy-0.5f)*(fy-0.5f);
    wz[0] = 0.5f*(1.5f-fz)*(1.5f-fz); wz[1] = 0.75f-(fz-1.f)*(fz-1.f); wz[2] = 0.5f*(fz-0.5f)*(fz-0.5f);
    const long tbase = (long)t * CELLS;
    #pragma unroll
    for (int ii = 0; ii < 3; ++ii) {
        const long xoff = tbase + (long)(b.x + ii) * (G * G);
        #pragma unroll
        for (int jj = 0; jj < 3; ++jj) {
            const float wij = wx[ii] * wy[jj];
            const long yoff = xoff + (long)(b.y + jj) * G;
            #pragma unroll
            for (int kk = 0; kk < 3; ++kk) {
                const float w = wij * wz[kk];
                const long idx = yoff + (b.z + kk);
                atomicAdd(&grids[idx], w);
                atomicAdd(&gdef[idx*3+0], w * dx);
                atomicAdd(&gdef[idx*3+1], w * dy);
                atomicAdd(&gdef[idx*3+2], w * dz);
            }
        }
    }
}

extern "C" void kernel_launch(void* const* d_in, const int* in_sizes, int n_in,
                              void* d_out, int out_size, void* d_ws, size_t ws_size,
                              hipStream_t stream)
{
    const float* xs  = (const float*)d_in[0];
    const float* def = (const float*)d_in[1];
    float* out = (float*)d_out;

    const int T = (int)(out_size / ((long)CELLS * 4));
    const int N = in_sizes[0] / (3 * T);

    float* grids = out;
    float* gdef  = out + (long)T * CELLS;

    const size_t szA    = (size_t)T * N * sizeof(float4);     // 12.8 MB
    const size_t szB    = (size_t)T * N * sizeof(float2);     //  6.4 MB
    const size_t szArr  = (size_t)T * BUCKETS * sizeof(int);  // 16 MB
    const size_t szSums = (size_t)T * 128 * sizeof(int);
    const size_t szRank = (size_t)T * N * sizeof(int);        //  3.2 MB
    const size_t need   = szA + szB + szArr + szSums + szRank;

    if (ws_size >= need) {
        char* ws = (char*)d_ws;
        float4* sA   = (float4*)ws;  ws += szA;
        float2* sB   = (float2*)ws;  ws += szB;
        int*    arr  = (int*)ws;     ws += szArr;
        int*    sums = (int*)ws;     ws += szSums;
        int*    rank = (int*)ws;

        hipMemsetAsync(arr, 0, szArr, stream);

        dim3 pgrid((N + 255) / 256, T);
        hist_rank    <<<pgrid, dim3(256), 0, stream>>>(xs, arr, rank, N);
        scan1        <<<dim3(BUCKETS / 4096, T), dim3(256), 0, stream>>>(arr, sums);
        scan2        <<<dim3(T), dim3(128), 0, stream>>>(sums);
        scatter_cells<<<pgrid, dim3(256), 0, stream>>>(xs, def, arr, sums, rank,
                                                       sA, sB, N);
        // waves = 16384 cols x 2 halves = 32768; 4 waves/block -> 8192 blocks
        gather_cells6<<<dim3(CELLS / 256, T), dim3(256), 0, stream>>>(
            sA, sB, arr, sums, grids, gdef, N);
        return;
    }

    hipMemsetAsync(d_out, 0, (size_t)out_size * sizeof(float), stream);
    dim3 grid((N + 255) / 256, T);
    p2g_direct<<<grid, dim3(256), 0, stream>>>(xs, def, grids, gdef, N);
}

// Round 26
// 217.862 us; speedup vs baseline: 1.0328x; 1.0328x over previous
//
#include <hip/hip_runtime.h>

// MPM P2G, quadratic B-spline, 3x3x3 stencil.
// Bucket-4 sort + cooperative gather (v11 = v9 + 32B packed payload record):
//   pre-pass: counting-sort by 4-z-cell BUCKET; hist's atomicAdd RETURNS the
//             particle's rank -> scatter uses start[bucket]+rank (NO atomic).
//             Payload = ONE 32B-aligned record (2 adjacent float4s) -> 1 cache
//             line per particle on scatter AND stage (was 2: sA/sB far apart).
//   gather:   v9-exact (b32 dependent ws read, accumulate unrolled x2 — x4
//             regressed in r25).
// No atomics in gather, write-once coalesced stores.
//
// Outputs (concatenated in d_out, fp32):
//   grids [T,G,G,G]   -> d_out[0 .. T*G^3)
//   gdef  [T,G,G,G,3] -> d_out[T*G^3 .. 4*T*G^3)

constexpr int   G       = 128;
constexpr int   CELLS   = G * G * G;      // 2,097,152
constexpr int   BUCKETS = CELLS / 4;      // 524,288 per timestep
constexpr float MINN    = -15.0f;
constexpr float EXTENT  = 40.0f;

__device__ __forceinline__ int3 base_cell(float x, float y, float z,
                                          float& fx, float& fy, float& fz)
{
    const float scale = (float)G / EXTENT;
    const float Xp = (x - MINN) * scale;
    const float Yp = (y - MINN) * scale;
    const float Zp = (z - MINN) * scale;
    int bx = (int)floorf(Xp - 0.5f);
    int by = (int)floorf(Yp - 0.5f);
    int bz = (int)floorf(Zp - 0.5f);
    // f from the UNclamped base (matches reference); clamp affects indices only
    fx = Xp - (float)bx; fy = Yp - (float)by; fz = Zp - (float)bz;
    bx = min(max(bx, 0), G - 3);
    by = min(max(by, 0), G - 3);
    bz = min(max(bz, 0), G - 3);
    return make_int3(bx, by, bz);
}

__device__ __forceinline__ float wsel(float f, int d)
{
    const float r0 = 1.5f - f, r1 = f - 1.0f, r2 = f - 0.5f;
    const float w0 = 0.5f * r0 * r0;
    const float w1 = 0.75f - r1 * r1;
    const float w2 = 0.5f * r2 * r2;
    return d == 0 ? w0 : (d == 1 ? w1 : w2);
}

// ---- K1: per-bucket histogram; atomic return value = in-bucket rank ---------
__global__ void __launch_bounds__(256)
hist_rank(const float* __restrict__ xs, int* __restrict__ arr,
          int* __restrict__ rank, int N)
{
    const int p = blockIdx.x * blockDim.x + threadIdx.x;
    const int t = blockIdx.y;
    if (p >= N) return;
    const long i = (long)t * N + p;
    float fx, fy, fz;
    int3 b = base_cell(xs[i*3], xs[i*3+1], xs[i*3+2], fx, fy, fz);
    const int bucket = (b.x << 12) + (b.y << 5) + (b.z >> 2);
    rank[i] = atomicAdd(&arr[(long)t * BUCKETS + bucket], 1);
}

// ---- K2a: per-4096-chunk exclusive scan (in place) + chunk totals -----------
__global__ void __launch_bounds__(256)
scan1(int* __restrict__ arr, int* __restrict__ sums)
{
    const int t = blockIdx.y, tid = threadIdx.x;
    int* a = arr + (long)t * BUCKETS + (long)blockIdx.x * 4096 + tid * 16;
    int local[16], s = 0;
    #pragma unroll
    for (int i = 0; i < 16; ++i) { const int v = a[i]; local[i] = s; s += v; }
    __shared__ int part[256];
    part[tid] = s;
    __syncthreads();
    const int own = s;
    for (int d = 1; d < 256; d <<= 1) {
        int v = (tid >= d) ? part[tid - d] : 0;
        __syncthreads();
        part[tid] += v;
        __syncthreads();
    }
    const int excl = part[tid] - own;
    #pragma unroll
    for (int i = 0; i < 16; ++i) a[i] = excl + local[i];
    if (tid == 255) sums[t * 128 + blockIdx.x] = part[255];
}

// ---- K2b: exclusive scan of the 128 chunk totals per timestep ---------------
__global__ void __launch_bounds__(128)
scan2(int* __restrict__ sums)
{
    const int t = blockIdx.x, tid = threadIdx.x;   // 128 threads, 1 each
    const int v = sums[t * 128 + tid];
    __shared__ int part[128];
    part[tid] = v;
    __syncthreads();
    for (int d = 1; d < 128; d <<= 1) {
        int u = (tid >= d) ? part[tid - d] : 0;
        __syncthreads();
        part[tid] += u;
        __syncthreads();
    }
    sums[t * 128 + tid] = part[tid] - v;           // exclusive
}

// ---- K3: scatter via start[bucket]+rank (no atomics); 32B packed record -----
__global__ void __launch_bounds__(256)
scatter_cells(const float* __restrict__ xs, const float* __restrict__ def,
              const int* __restrict__ arr, const int* __restrict__ sums,
              const int* __restrict__ rank,
              float4* __restrict__ sP, int N)
{
    const int p = blockIdx.x * blockDim.x + threadIdx.x;
    const int t = blockIdx.y;
    if (p >= N) return;
    const long i = (long)t * N + p;
    const float x = xs[i*3], y = xs[i*3+1], z = xs[i*3+2];
    float fx, fy, fz;
    int3 b = base_cell(x, y, z, fx, fy, fz);
    const float Zp = (z - MINN) * ((float)G / EXTENT);
    const int bucket = (b.x << 12) + (b.y << 5) + (b.z >> 2);
    const int slot = arr[(long)t * BUCKETS + bucket]
                   + sums[t * 128 + (bucket >> 12)] + rank[i];
    const long o = ((long)t * N + slot) * 2;       // 32B record = 2 float4s
    sP[o]     = make_float4(fx, fy, Zp, def[i*3]);
    sP[o + 1] = make_float4(def[i*3+1], def[i*3+2], 0.0f, 0.0f);
}

// ---- K4: v9-exact gather (unroll x2); packed-record stage loads -------------
__global__ void __launch_bounds__(256)
gather_cells6(const float4* __restrict__ sP,
              const int* __restrict__ arr, const int* __restrict__ sums,
              float* __restrict__ grids, float* __restrict__ gdef, int N)
{
    const int wid  = threadIdx.x >> 6;
    const int lane = threadIdx.x & 63;
    const int g    = lane >> 4;                  // group 0..3
    const int zl   = lane & 15;                  // z within group
    const int t = blockIdx.y;
    const int W = blockIdx.x * 4 + wid;
    const int col = W >> 1;                      // (cx,cy) column
    const int zbase = (W & 1) << 6;              // 0 or 64
    const int cy = col & (G - 1);
    const int cx = col >> 7;
    const int cz = zbase + lane;                 // lane's output z (g*16+zl)

    __shared__ int2   descBC[4][4][9];           // [wid][g][r] {begin, count}
    __shared__ float4 rec[4][4][17];             // [wid][g][slot] {bz,d0,d1,d2}
    __shared__ float  ws[4][3][4][17];           // [wid][k][g][slot]

    const int* a  = arr + (long)t * BUCKETS;
    const int* sm = sums + t * 128;
    const long pbase = (long)t * N;

    // --- 36 segment descriptors (4 groups x 9 rows), lanes 0..35 -------------
    // group window z [Z0, Z0+15] -> buckets [bb-1, bb+3]; with START offsets:
    // range = [start(bb-1), start(bb+4)) -> c0 = rb+bb-1, c1 = rb+bb+4.
    // Over-coverage is k-filtered in accumulate.
    if (lane < 36) {
        const int g2 = lane / 9;                 // magic-mul
        const int r2 = lane - 9 * g2;
        const int rx = cx - 2 + r2 / 3;
        const int ry = cy - 2 + r2 % 3;
        int beg = 0, cnt = 0;
        if (rx >= 0 && ry >= 0) {
            const int rb = (rx << 12) + (ry << 5);
            const int bb = (zbase >> 2) + (g2 << 2);
            const int c1 = rb + bb + 4;          // start of bucket past window
            const int e  = a[c1] + sm[c1 >> 12];
            const int c0 = rb + bb - 1;          // start of first window bucket
            beg = (c0 >= 0) ? (a[c0] + sm[c0 >> 12]) : 0;
            cnt = max(e - beg, 0);
        }
        descBC[wid][g2][r2] = make_int2(beg, cnt);
    }
    // same-wave DS program order: reads below see the writes above.

    // --- per-lane prefix from LDS broadcast reads ----------------------------
    const int2 d0_ = descBC[wid][g][0], d1_ = descBC[wid][g][1],
               d2_ = descBC[wid][g][2], d3_ = descBC[wid][g][3],
               d4_ = descBC[wid][g][4], d5_ = descBC[wid][g][5],
               d6_ = descBC[wid][g][6], d7_ = descBC[wid][g][7],
               d8_ = descBC[wid][g][8];
    const int p1 = d0_.y;
    const int p2 = p1 + d1_.y;
    const int p3 = p2 + d2_.y;
    const int p4 = p3 + d3_.y;
    const int p5 = p4 + d4_.y;
    const int p6 = p5 + d5_.y;
    const int p7 = p6 + d6_.y;
    const int p8 = p7 + d7_.y;
    const int tot = p8 + d8_.y;                  // group total (uniform in group)
    const int adj0 = d0_.x;
    const int adj1 = d1_.x - p1;
    const int adj2 = d2_.x - p2;
    const int adj3 = d3_.x - p3;
    const int adj4 = d4_.x - p4;
    const int adj5 = d5_.x - p5;
    const int adj6 = d6_.x - p6;
    const int adj7 = d7_.x - p7;
    const int adj8 = d8_.x - p8;

    // wave-max of the 4 group totals
    int mt = max(tot, __shfl_xor(tot, 16));
    mt = max(mt, __shfl_xor(mt, 32));

    float m = 0.f, v0 = 0.f, v1 = 0.f, v2 = 0.f;

    for (int p0 = 0; p0 < mt; p0 += 16) {
        // ---- stage: each group fills up to 16 slots, weights computed once --
        const int j = p0 + zl;
        if (j < tot) {
            const int g1_ = (j >= p1), g2_ = (j >= p2), g3_ = (j >= p3),
                      g4_ = (j >= p4), g5_ = (j >= p5), g6_ = (j >= p6),
                      g7_ = (j >= p7), g8_ = (j >= p8);
            int ad = adj0;
            ad = g1_ ? adj1 : ad;  ad = g2_ ? adj2 : ad;  ad = g3_ ? adj3 : ad;
            ad = g4_ ? adj4 : ad;  ad = g5_ ? adj5 : ad;  ad = g6_ ? adj6 : ad;
            ad = g7_ ? adj7 : ad;  ad = g8_ ? adj8 : ad;
            const int dp = 10 - g1_ - g2_ - 2*g3_ - g4_ - g5_ - 2*g6_ - g7_ - g8_;
            const int idx = j + ad;

            const long ro = (pbase + idx) * 2;   // 32B record, same cache line
            const float4 A = sP[ro];             // {fx, fy, Zp, d0}
            const float4 B = sP[ro + 1];         // {d1, d2, -, -}
            const float bzf = floorf(A.z - 0.5f);
            const float fz  = A.z - bzf;
            const float wxy = wsel(A.x, dp >> 2) * wsel(A.y, dp & 3);
            const float q0 = 1.5f - fz, q1 = fz - 1.0f, q2 = fz - 0.5f;
            rec[wid][g][zl] =
                make_float4(__int_as_float((int)bzf), A.w, B.x, B.y);
            ws[wid][0][g][zl] = wxy * (0.5f * q0 * q0);
            ws[wid][1][g][zl] = wxy * (0.75f - q1 * q1);
            ws[wid][2][g][zl] = wxy * (0.5f * q2 * q2);
        }
        // ---- accumulate this batch, v6 trip body, unrolled x2 ---------------
        const int cc = min(tot - p0, 16);
        int p = 0;
        for (; p + 1 < cc; p += 2) {
            const float4 Ra = rec[wid][g][p];
            const float4 Rb = rec[wid][g][p + 1];
            const int ka_ = cz - __float_as_int(Ra.x);
            const int kb_ = cz - __float_as_int(Rb.x);
            const int kca = min(max(ka_, 0), 2);
            const int kcb = min(max(kb_, 0), 2);
            const float wsa = ws[wid][kca][g][p];
            const float wsb = ws[wid][kcb][g][p + 1];
            const float wa = ((unsigned)ka_ <= 2u) ? wsa : 0.0f;
            const float wb = ((unsigned)kb_ <= 2u) ? wsb : 0.0f;
            m  += wa;            v0 += wa * Ra.y;
            v1 += wa * Ra.z;     v2 += wa * Ra.w;
            m  += wb;            v0 += wb * Rb.y;
            v1 += wb * Rb.z;     v2 += wb * Rb.w;
        }
        if (p < cc) {
            const float4 R = rec[wid][g][p];
            const int k  = cz - __float_as_int(R.x);
            const int kc = min(max(k, 0), 2);
            const float wsv = ws[wid][kc][g][p];
            const float w = ((unsigned)k <= 2u) ? wsv : 0.0f;
            m  += w;             v0 += w * R.y;
            v1 += w * R.z;       v2 += w * R.w;
        }
    }

    // flush: lane owns cell (t, cx, cy, cz) -> write-once coalesced stores
    const long gidx = (long)t * CELLS + ((long)col << 7) + cz;
    grids[gidx]      = m;
    gdef[gidx*3 + 0] = v0;
    gdef[gidx*3 + 1] = v1;
    gdef[gidx*3 + 2] = v2;
}

// ---- last-resort fallback: direct global atomics ----------------------------
__global__ void __launch_bounds__(256)
p2g_direct(const float* __restrict__ xs, const float* __restrict__ def,
           float* __restrict__ grids, float* __restrict__ gdef, int N)
{
    const int p = blockIdx.x * blockDim.x + threadIdx.x;
    const int t = blockIdx.y;
    if (p >= N) return;
    const long i = (long)t * N + p;
    const float dx = def[i*3], dy = def[i*3+1], dz = def[i*3+2];
    float fx, fy, fz;
    int3 b = base_cell(xs[i*3], xs[i*3+1], xs[i*3+2], fx, fy, fz);
    float wx[3], wy[3], wz[3];
    wx[0] = 0.5f*(1.5f-fx)*(1.5f-fx); wx[1] = 0.75f-(fx-1.f)*(fx-1.f); wx[2] = 0.5f*(fx-0.5f)*(fx-0.5f);
    wy[0] = 0.5f*(1.5f-fy)*(1.5f-fy); wy[1] = 0.75f-(fy-1.f)*(fy-1.f); wy[2] = 0.5f*(fy-0.5f)*(fy-0.5f);
    wz[0] = 0.5f*(1.5f-fz)*(1.5f-fz); wz[1] = 0.75f-(fz-1.f)*(fz-1.f); wz[2] = 0.5f*(fz-0.5f)*(fz-0.5f);
    const long tbase = (long)t * CELLS;
    #pragma unroll
    for (int ii = 0; ii < 3; ++ii) {
        const long xoff = tbase + (long)(b.x + ii) * (G * G);
        #pragma unroll
        for (int jj = 0; jj < 3; ++jj) {
            const float wij = wx[ii] * wy[jj];
            const long yoff = xoff + (long)(b.y + jj) * G;
            #pragma unroll
            for (int kk = 0; kk < 3; ++kk) {
                const float w = wij * wz[kk];
                const long idx = yoff + (b.z + kk);
                atomicAdd(&grids[idx], w);
                atomicAdd(&gdef[idx*3+0], w * dx);
                atomicAdd(&gdef[idx*3+1], w * dy);
                atomicAdd(&gdef[idx*3+2], w * dz);
            }
        }
    }
}

extern "C" void kernel_launch(void* const* d_in, const int* in_sizes, int n_in,
                              void* d_out, int out_size, void* d_ws, size_t ws_size,
                              hipStream_t stream)
{
    const float* xs  = (const float*)d_in[0];
    const float* def = (const float*)d_in[1];
    float* out = (float*)d_out;

    const int T = (int)(out_size / ((long)CELLS * 4));
    const int N = in_sizes[0] / (3 * T);

    float* grids = out;
    float* gdef  = out + (long)T * CELLS;

    const size_t szP    = (size_t)T * N * 2 * sizeof(float4); // 25.6 MB
    const size_t szArr  = (size_t)T * BUCKETS * sizeof(int);  // 16 MB
    const size_t szSums = (size_t)T * 128 * sizeof(int);
    const size_t szRank = (size_t)T * N * sizeof(int);        //  3.2 MB
    const size_t need   = szP + szArr + szSums + szRank;

    if (ws_size >= need) {
        char* ws = (char*)d_ws;
        float4* sP   = (float4*)ws;  ws += szP;
        int*    arr  = (int*)ws;     ws += szArr;
        int*    sums = (int*)ws;     ws += szSums;
        int*    rank = (int*)ws;

        hipMemsetAsync(arr, 0, szArr, stream);

        dim3 pgrid((N + 255) / 256, T);
        hist_rank    <<<pgrid, dim3(256), 0, stream>>>(xs, arr, rank, N);
        scan1        <<<dim3(BUCKETS / 4096, T), dim3(256), 0, stream>>>(arr, sums);
        scan2        <<<dim3(T), dim3(128), 0, stream>>>(sums);
        scatter_cells<<<pgrid, dim3(256), 0, stream>>>(xs, def, arr, sums, rank,
                                                       sP, N);
        // waves = 16384 cols x 2 halves = 32768; 4 waves/block -> 8192 blocks
        gather_cells6<<<dim3(CELLS / 256, T), dim3(256), 0, stream>>>(
            sP, arr, sums, grids, gdef, N);
        return;
    }

    hipMemsetAsync(d_out, 0, (size_t)out_size * sizeof(float), stream);
    dim3 grid((N + 255) / 256, T);
    p2g_direct<<<grid, dim3(256), 0, stream>>>(xs, def, grids, gdef, N);
}

// Round 27
// 216.659 us; speedup vs baseline: 1.0386x; 1.0056x over previous
//
#include <hip/hip_runtime.h>

// MPM P2G, quadratic B-spline, 3x3x3 stencil.
// Bucket-4 sort + cooperative gather (v12 = v11 + fused 32B LDS record):
//   pre-pass: counting-sort by 4-z-cell BUCKET; hist's atomicAdd RETURNS the
//             particle's rank -> scatter uses start[bucket]+rank (NO atomic).
//             Payload = ONE 32B record (2 adjacent float4s, 1 line/particle).
//   gather:   v9 accumulate (b32 dependent ws read, unroll x2). Stage now
//             writes ONE 32B LDS slot {bz,d0,d1,d2,w0,w1,w2,-} via 2x
//             ds_write_b128 (was b128 + 3x b32). Read pattern unchanged:
//             b128 rec + dependent b32 ws at slot*32+16+4k.
// No atomics in gather, write-once coalesced stores.
//
// Outputs (concatenated in d_out, fp32):
//   grids [T,G,G,G]   -> d_out[0 .. T*G^3)
//   gdef  [T,G,G,G,3] -> d_out[T*G^3 .. 4*T*G^3)

constexpr int   G       = 128;
constexpr int   CELLS   = G * G * G;      // 2,097,152
constexpr int   BUCKETS = CELLS / 4;      // 524,288 per timestep
constexpr float MINN    = -15.0f;
constexpr float EXTENT  = 40.0f;

__device__ __forceinline__ int3 base_cell(float x, float y, float z,
                                          float& fx, float& fy, float& fz)
{
    const float scale = (float)G / EXTENT;
    const float Xp = (x - MINN) * scale;
    const float Yp = (y - MINN) * scale;
    const float Zp = (z - MINN) * scale;
    int bx = (int)floorf(Xp - 0.5f);
    int by = (int)floorf(Yp - 0.5f);
    int bz = (int)floorf(Zp - 0.5f);
    // f from the UNclamped base (matches reference); clamp affects indices only
    fx = Xp - (float)bx; fy = Yp - (float)by; fz = Zp - (float)bz;
    bx = min(max(bx, 0), G - 3);
    by = min(max(by, 0), G - 3);
    bz = min(max(bz, 0), G - 3);
    return make_int3(bx, by, bz);
}

__device__ __forceinline__ float wsel(float f, int d)
{
    const float r0 = 1.5f - f, r1 = f - 1.0f, r2 = f - 0.5f;
    const float w0 = 0.5f * r0 * r0;
    const float w1 = 0.75f - r1 * r1;
    const float w2 = 0.5f * r2 * r2;
    return d == 0 ? w0 : (d == 1 ? w1 : w2);
}

// ---- K1: per-bucket histogram; atomic return value = in-bucket rank ---------
__global__ void __launch_bounds__(256)
hist_rank(const float* __restrict__ xs, int* __restrict__ arr,
          int* __restrict__ rank, int N)
{
    const int p = blockIdx.x * blockDim.x + threadIdx.x;
    const int t = blockIdx.y;
    if (p >= N) return;
    const long i = (long)t * N + p;
    float fx, fy, fz;
    int3 b = base_cell(xs[i*3], xs[i*3+1], xs[i*3+2], fx, fy, fz);
    const int bucket = (b.x << 12) + (b.y << 5) + (b.z >> 2);
    rank[i] = atomicAdd(&arr[(long)t * BUCKETS + bucket], 1);
}

// ---- K2a: per-4096-chunk exclusive scan (in place) + chunk totals -----------
__global__ void __launch_bounds__(256)
scan1(int* __restrict__ arr, int* __restrict__ sums)
{
    const int t = blockIdx.y, tid = threadIdx.x;
    int* a = arr + (long)t * BUCKETS + (long)blockIdx.x * 4096 + tid * 16;
    int local[16], s = 0;
    #pragma unroll
    for (int i = 0; i < 16; ++i) { const int v = a[i]; local[i] = s; s += v; }
    __shared__ int part[256];
    part[tid] = s;
    __syncthreads();
    const int own = s;
    for (int d = 1; d < 256; d <<= 1) {
        int v = (tid >= d) ? part[tid - d] : 0;
        __syncthreads();
        part[tid] += v;
        __syncthreads();
    }
    const int excl = part[tid] - own;
    #pragma unroll
    for (int i = 0; i < 16; ++i) a[i] = excl + local[i];
    if (tid == 255) sums[t * 128 + blockIdx.x] = part[255];
}

// ---- K2b: exclusive scan of the 128 chunk totals per timestep ---------------
__global__ void __launch_bounds__(128)
scan2(int* __restrict__ sums)
{
    const int t = blockIdx.x, tid = threadIdx.x;   // 128 threads, 1 each
    const int v = sums[t * 128 + tid];
    __shared__ int part[128];
    part[tid] = v;
    __syncthreads();
    for (int d = 1; d < 128; d <<= 1) {
        int u = (tid >= d) ? part[tid - d] : 0;
        __syncthreads();
        part[tid] += u;
        __syncthreads();
    }
    sums[t * 128 + tid] = part[tid] - v;           // exclusive
}

// ---- K3: scatter via start[bucket]+rank (no atomics); 32B packed record -----
__global__ void __launch_bounds__(256)
scatter_cells(const float* __restrict__ xs, const float* __restrict__ def,
              const int* __restrict__ arr, const int* __restrict__ sums,
              const int* __restrict__ rank,
              float4* __restrict__ sP, int N)
{
    const int p = blockIdx.x * blockDim.x + threadIdx.x;
    const int t = blockIdx.y;
    if (p >= N) return;
    const long i = (long)t * N + p;
    const float x = xs[i*3], y = xs[i*3+1], z = xs[i*3+2];
    float fx, fy, fz;
    int3 b = base_cell(x, y, z, fx, fy, fz);
    const float Zp = (z - MINN) * ((float)G / EXTENT);
    const int bucket = (b.x << 12) + (b.y << 5) + (b.z >> 2);
    const int slot = arr[(long)t * BUCKETS + bucket]
                   + sums[t * 128 + (bucket >> 12)] + rank[i];
    const long o = ((long)t * N + slot) * 2;       // 32B record = 2 float4s
    sP[o]     = make_float4(fx, fy, Zp, def[i*3]);
    sP[o + 1] = make_float4(def[i*3+1], def[i*3+2], 0.0f, 0.0f);
}

// ---- K4: v9 gather with fused 32B LDS record --------------------------------
__global__ void __launch_bounds__(256)
gather_cells6(const float4* __restrict__ sP,
              const int* __restrict__ arr, const int* __restrict__ sums,
              float* __restrict__ grids, float* __restrict__ gdef, int N)
{
    const int wid  = threadIdx.x >> 6;
    const int lane = threadIdx.x & 63;
    const int g    = lane >> 4;                  // group 0..3
    const int zl   = lane & 15;                  // z within group
    const int t = blockIdx.y;
    const int W = blockIdx.x * 4 + wid;
    const int col = W >> 1;                      // (cx,cy) column
    const int zbase = (W & 1) << 6;              // 0 or 64
    const int cy = col & (G - 1);
    const int cx = col >> 7;
    const int cz = zbase + lane;                 // lane's output z (g*16+zl)

    __shared__ int2   descBC[4][4][9];           // [wid][g][r] {begin, count}
    // fused record: [wid][g][slot][8] = {bz,d0,d1,d2, w0,w1,w2,pad}
    __shared__ float  rws[4][4][17][8];          // 4x4x17x32B = 8704B/wave-set

    const int* a  = arr + (long)t * BUCKETS;
    const int* sm = sums + t * 128;
    const long pbase = (long)t * N;

    // --- 36 segment descriptors (4 groups x 9 rows), lanes 0..35 -------------
    // group window z [Z0, Z0+15] -> buckets [bb-1, bb+3]; with START offsets:
    // range = [start(bb-1), start(bb+4)) -> c0 = rb+bb-1, c1 = rb+bb+4.
    // Over-coverage is k-filtered in accumulate.
    if (lane < 36) {
        const int g2 = lane / 9;                 // magic-mul
        const int r2 = lane - 9 * g2;
        const int rx = cx - 2 + r2 / 3;
        const int ry = cy - 2 + r2 % 3;
        int beg = 0, cnt = 0;
        if (rx >= 0 && ry >= 0) {
            const int rb = (rx << 12) + (ry << 5);
            const int bb = (zbase >> 2) + (g2 << 2);
            const int c1 = rb + bb + 4;          // start of bucket past window
            const int e  = a[c1] + sm[c1 >> 12];
            const int c0 = rb + bb - 1;          // start of first window bucket
            beg = (c0 >= 0) ? (a[c0] + sm[c0 >> 12]) : 0;
            cnt = max(e - beg, 0);
        }
        descBC[wid][g2][r2] = make_int2(beg, cnt);
    }
    // same-wave DS program order: reads below see the writes above.

    // --- per-lane prefix from LDS broadcast reads ----------------------------
    const int2 d0_ = descBC[wid][g][0], d1_ = descBC[wid][g][1],
               d2_ = descBC[wid][g][2], d3_ = descBC[wid][g][3],
               d4_ = descBC[wid][g][4], d5_ = descBC[wid][g][5],
               d6_ = descBC[wid][g][6], d7_ = descBC[wid][g][7],
               d8_ = descBC[wid][g][8];
    const int p1 = d0_.y;
    const int p2 = p1 + d1_.y;
    const int p3 = p2 + d2_.y;
    const int p4 = p3 + d3_.y;
    const int p5 = p4 + d4_.y;
    const int p6 = p5 + d5_.y;
    const int p7 = p6 + d6_.y;
    const int p8 = p7 + d7_.y;
    const int tot = p8 + d8_.y;                  // group total (uniform in group)
    const int adj0 = d0_.x;
    const int adj1 = d1_.x - p1;
    const int adj2 = d2_.x - p2;
    const int adj3 = d3_.x - p3;
    const int adj4 = d4_.x - p4;
    const int adj5 = d5_.x - p5;
    const int adj6 = d6_.x - p6;
    const int adj7 = d7_.x - p7;
    const int adj8 = d8_.x - p8;

    // wave-max of the 4 group totals
    int mt = max(tot, __shfl_xor(tot, 16));
    mt = max(mt, __shfl_xor(mt, 32));

    float m = 0.f, v0 = 0.f, v1 = 0.f, v2 = 0.f;

    for (int p0 = 0; p0 < mt; p0 += 16) {
        // ---- stage: each group fills up to 16 slots, 2x ds_write_b128 -------
        const int j = p0 + zl;
        if (j < tot) {
            const int g1_ = (j >= p1), g2_ = (j >= p2), g3_ = (j >= p3),
                      g4_ = (j >= p4), g5_ = (j >= p5), g6_ = (j >= p6),
                      g7_ = (j >= p7), g8_ = (j >= p8);
            int ad = adj0;
            ad = g1_ ? adj1 : ad;  ad = g2_ ? adj2 : ad;  ad = g3_ ? adj3 : ad;
            ad = g4_ ? adj4 : ad;  ad = g5_ ? adj5 : ad;  ad = g6_ ? adj6 : ad;
            ad = g7_ ? adj7 : ad;  ad = g8_ ? adj8 : ad;
            const int dp = 10 - g1_ - g2_ - 2*g3_ - g4_ - g5_ - 2*g6_ - g7_ - g8_;
            const int idx = j + ad;

            const long ro = (pbase + idx) * 2;   // 32B record, same cache line
            const float4 A = sP[ro];             // {fx, fy, Zp, d0}
            const float4 B = sP[ro + 1];         // {d1, d2, -, -}
            const float bzf = floorf(A.z - 0.5f);
            const float fz  = A.z - bzf;
            const float wxy = wsel(A.x, dp >> 2) * wsel(A.y, dp & 3);
            const float q0 = 1.5f - fz, q1 = fz - 1.0f, q2 = fz - 0.5f;
            float4* slot4 = (float4*)rws[wid][g][zl];
            slot4[0] = make_float4(__int_as_float((int)bzf), A.w, B.x, B.y);
            slot4[1] = make_float4(wxy * (0.5f * q0 * q0),
                                   wxy * (0.75f - q1 * q1),
                                   wxy * (0.5f * q2 * q2), 0.0f);
        }
        // ---- accumulate: b128 rec + dependent b32 ws (v9 shape), unroll x2 --
        const int cc = min(tot - p0, 16);
        int p = 0;
        for (; p + 1 < cc; p += 2) {
            const float4 Ra = *(const float4*)rws[wid][g][p];
            const float4 Rb = *(const float4*)rws[wid][g][p + 1];
            const int ka_ = cz - __float_as_int(Ra.x);
            const int kb_ = cz - __float_as_int(Rb.x);
            const int kca = min(max(ka_, 0), 2);
            const int kcb = min(max(kb_, 0), 2);
            const float wsa = rws[wid][g][p][4 + kca];
            const float wsb = rws[wid][g][p + 1][4 + kcb];
            const float wa = ((unsigned)ka_ <= 2u) ? wsa : 0.0f;
            const float wb = ((unsigned)kb_ <= 2u) ? wsb : 0.0f;
            m  += wa;            v0 += wa * Ra.y;
            v1 += wa * Ra.z;     v2 += wa * Ra.w;
            m  += wb;            v0 += wb * Rb.y;
            v1 += wb * Rb.z;     v2 += wb * Rb.w;
        }
        if (p < cc) {
            const float4 R = *(const float4*)rws[wid][g][p];
            const int k  = cz - __float_as_int(R.x);
            const int kc = min(max(k, 0), 2);
            const float wsv = rws[wid][g][p][4 + kc];
            const float w = ((unsigned)k <= 2u) ? wsv : 0.0f;
            m  += w;             v0 += w * R.y;
            v1 += w * R.z;       v2 += w * R.w;
        }
    }

    // flush: lane owns cell (t, cx, cy, cz) -> write-once coalesced stores
    const long gidx = (long)t * CELLS + ((long)col << 7) + cz;
    grids[gidx]      = m;
    gdef[gidx*3 + 0] = v0;
    gdef[gidx*3 + 1] = v1;
    gdef[gidx*3 + 2] = v2;
}

// ---- last-resort fallback: direct global atomics ----------------------------
__global__ void __launch_bounds__(256)
p2g_direct(const float* __restrict__ xs, const float* __restrict__ def,
           float* __restrict__ grids, float* __restrict__ gdef, int N)
{
    const int p = blockIdx.x * blockDim.x + threadIdx.x;
    const int t = blockIdx.y;
    if (p >= N) return;
    const long i = (long)t * N + p;
    const float dx = def[i*3], dy = def[i*3+1], dz = def[i*3+2];
    float fx, fy, fz;
    int3 b = base_cell(xs[i*3], xs[i*3+1], xs[i*3+2], fx, fy, fz);
    float wx[3], wy[3], wz[3];
    wx[0] = 0.5f*(1.5f-fx)*(1.5f-fx); wx[1] = 0.75f-(fx-1.f)*(fx-1.f); wx[2] = 0.5f*(fx-0.5f)*(fx-0.5f);
    wy[0] = 0.5f*(1.5f-fy)*(1.5f-fy); wy[1] = 0.75f-(fy-1.f)*(fy-1.f); wy[2] = 0.5f*(fy-0.5f)*(fy-0.5f);
    wz[0] = 0.5f*(1.5f-fz)*(1.5f-fz); wz[1] = 0.75f-(fz-1.f)*(fz-1.f); wz[2] = 0.5f*(fz-0.5f)*(fz-0.5f);
    const long tbase = (long)t * CELLS;
    #pragma unroll
    for (int ii = 0; ii < 3; ++ii) {
        const long xoff = tbase + (long)(b.x + ii) * (G * G);
        #pragma unroll
        for (int jj = 0; jj < 3; ++jj) {
            const float wij = wx[ii] * wy[jj];
            const long yoff = xoff + (long)(b.y + jj) * G;
            #pragma unroll
            for (int kk = 0; kk < 3; ++kk) {
                const float w = wij * wz[kk];
                const long idx = yoff + (b.z + kk);
                atomicAdd(&grids[idx], w);
                atomicAdd(&gdef[idx*3+0], w * dx);
                atomicAdd(&gdef[idx*3+1], w * dy);
                atomicAdd(&gdef[idx*3+2], w * dz);
            }
        }
    }
}

extern "C" void kernel_launch(void* const* d_in, const int* in_sizes, int n_in,
                              void* d_out, int out_size, void* d_ws, size_t ws_size,
                              hipStream_t stream)
{
    const float* xs  = (const float*)d_in[0];
    const float* def = (const float*)d_in[1];
    float* out = (float*)d_out;

    const int T = (int)(out_size / ((long)CELLS * 4));
    const int N = in_sizes[0] / (3 * T);

    float* grids = out;
    float* gdef  = out + (long)T * CELLS;

    const size_t szP    = (size_t)T * N * 2 * sizeof(float4); // 25.6 MB
    const size_t szArr  = (size_t)T * BUCKETS * sizeof(int);  // 16 MB
    const size_t szSums = (size_t)T * 128 * sizeof(int);
    const size_t szRank = (size_t)T * N * sizeof(int);        //  3.2 MB
    const size_t need   = szP + szArr + szSums + szRank;

    if (ws_size >= need) {
        char* ws = (char*)d_ws;
        float4* sP   = (float4*)ws;  ws += szP;
        int*    arr  = (int*)ws;     ws += szArr;
        int*    sums = (int*)ws;     ws += szSums;
        int*    rank = (int*)ws;

        hipMemsetAsync(arr, 0, szArr, stream);

        dim3 pgrid((N + 255) / 256, T);
        hist_rank    <<<pgrid, dim3(256), 0, stream>>>(xs, arr, rank, N);
        scan1        <<<dim3(BUCKETS / 4096, T), dim3(256), 0, stream>>>(arr, sums);
        scan2        <<<dim3(T), dim3(128), 0, stream>>>(sums);
        scatter_cells<<<pgrid, dim3(256), 0, stream>>>(xs, def, arr, sums, rank,
                                                       sP, N);
        // waves = 16384 cols x 2 halves = 32768; 4 waves/block -> 8192 blocks
        gather_cells6<<<dim3(CELLS / 256, T), dim3(256), 0, stream>>>(
            sP, arr, sums, grids, gdef, N);
        return;
    }

    hipMemsetAsync(d_out, 0, (size_t)out_size * sizeof(float), stream);
    dim3 grid((N + 255) / 256, T);
    p2g_direct<<<grid, dim3(256), 0, stream>>>(xs, def, grids, gdef, N);
}